// Round 10
// baseline (180.180 us; speedup 1.0000x reference)
//
#include <hip/hip_runtime.h>
#include <hip/hip_bf16.h>
#include <math.h>

#define BATCH 4
#define NQ 8192
#define KNB 8
#define K1 9            // keep 9: self filtered at loss merge
#define CAP 34          // u16 survivor slots/thread (68B stride: bank-safe on drains)
#define THSAMP 256      // theta subsample size per theta-partition
#define SPART 2         // theta partitions (disjoint subsamples, min-merged)
#define NB 256          // x-bins for counting sort
#define XMIN -4.5f
#define XSCALE (NB / 9.0f)
#define IDXMASK 8191u
#define KEYMASK 0xFFFFE000u  // sign+exp+10 mantissa bits; low 13 bits hold ORIG index
#define EPS_S 1e-3f     // gate slack >> fp32 error of the 3-fma score form

static __device__ __forceinline__ int binOf(float x) {
  int b = (int)((x - XMIN) * XSCALE);
  return min(max(b, 0), NB - 1);
}

#define CHAIN9(KEY) { unsigned kk = (KEY); \
  _Pragma("unroll") \
  for (int j = 0; j < K1; ++j) { \
    unsigned lo = min(kk, nk[j]); unsigned hi = max(kk, nk[j]); \
    nk[j] = lo; kk = hi; } }

#define CHAIN8(KEY) { unsigned kk = (KEY); \
  _Pragma("unroll") \
  for (int j = 0; j < KNB; ++j) { \
    unsigned lo = min(kk, nk[j]); unsigned hi = max(kk, nk[j]); \
    nk[j] = lo; kk = hi; } }

// drain survivors (sorted-domain idx j): recompute EXACT key, carry ORIG idx
#define DRAINS() { \
  for (int ii = 0; ii < cnt; ++ii) { \
    int j = sbuf[base + ii]; \
    float dx = qx - sxs[bq + j], dy = qy - sys[bq + j], dz = qz - szs[bq + j]; \
    float d = dx*dx + dy*dy + dz*dz; \
    unsigned key = (__float_as_uint(d) & KEYMASK) | ssi[bq + j]; \
    if (key < nk[K1-1]) CHAIN9(key); \
  } \
  cnt = 0; \
  if (nk[K1-1] != 0xFFFFFFFFu) { \
    float td = __uint_as_float(nk[K1-1] | 0x1FFFu); \
    thetaS = fminf(thetaS, 0.5f*(td - qq) + EPS_S); \
  } }

#define GPROC(SS, JLOCAL) { \
  if ((SS) <= thetaS) { sbuf[base + cnt] = (unsigned short)(JLOCAL); cnt++; } }

#define SCORE4(S0,S1,S2,S3, X,Y,Z,H) \
  float S0 = fmaf(nqx, X.x, fmaf(nqy, Y.x, fmaf(nqz, Z.x, H.x))); \
  float S1 = fmaf(nqx, X.y, fmaf(nqy, Y.y, fmaf(nqz, Z.y, H.y))); \
  float S2 = fmaf(nqx, X.z, fmaf(nqy, Y.z, fmaf(nqz, Z.z, H.z))); \
  float S3 = fmaf(nqx, X.w, fmaf(nqy, Y.w, fmaf(nqz, Z.w, H.w)));

// ---- 1. histogram of x-bins ----
__global__ __launch_bounds__(256) void hist_kernel(
    const float* __restrict__ pc, unsigned* __restrict__ hist)
{
  const int t = blockIdx.x * 256 + threadIdx.x;      // 0..32767
  const int b = t >> 13, n = t & (NQ - 1);
  const float x = pc[(size_t)b * 3 * NQ + n];
  atomicAdd(&hist[b * NB + binOf(x)], 1u);
}

// ---- 2. per-batch exclusive prefix (one block); hist becomes scatter cursor ----
__global__ __launch_bounds__(256) void prefix_kernel(
    unsigned* __restrict__ hist, unsigned* __restrict__ binStart)
{
  __shared__ unsigned sc[NB];
  const int t = threadIdx.x;
  for (int b = 0; b < BATCH; ++b) {
    const unsigned c = hist[b * NB + t];
    sc[t] = c;
    __syncthreads();
    for (int o = 1; o < NB; o <<= 1) {
      unsigned a = (t >= o) ? sc[t - o] : 0u;
      __syncthreads();
      sc[t] += a;
      __syncthreads();
    }
    const unsigned excl = sc[t] - c;
    binStart[b * (NB + 1) + t] = excl;
    hist[b * NB + t] = excl;                 // cursor for scatter
    if (t == NB - 1) binStart[b * (NB + 1) + NB] = sc[t];
    __syncthreads();
  }
}

// ---- 3. scatter into sorted-by-x arrays (+ h = 0.5||c||^2, orig idx) ----
__global__ __launch_bounds__(256) void scatter_kernel(
    const float* __restrict__ pc, unsigned* __restrict__ cursor,
    float* __restrict__ sxs, float* __restrict__ sys, float* __restrict__ szs,
    float* __restrict__ shs, unsigned* __restrict__ ssi)
{
  const int t = blockIdx.x * 256 + threadIdx.x;
  const int b = t >> 13, n = t & (NQ - 1);
  const float* __restrict__ px = pc + (size_t)b * 3 * NQ;
  const float x = px[n], y = px[NQ + n], z = px[2 * NQ + n];
  const unsigned pos = atomicAdd(&cursor[b * NB + binOf(x)], 1u);
  const int o = b * NQ + (int)pos;
  sxs[o] = x; sys[o] = y; szs[o] = z;
  shs[o] = 0.5f * (x * x + y * y + z * z);
  ssi[o] = (unsigned)n;
}

// ---- 4. theta bound: 9th of 256 x-stratified sorted samples, x2 disjoint ----
__global__ __launch_bounds__(256) void theta_kernel(
    const float* __restrict__ sxs, const float* __restrict__ sys,
    const float* __restrict__ szs, unsigned* __restrict__ thetaOut)
{
  __shared__ float swx[THSAMP], swy[THSAMP], swz[THSAMP];
  const int b = blockIdx.y, p = blockIdx.z;
  const int s = blockIdx.x * 256 + threadIdx.x;
  const int bq = b * NQ;
  const int tid = threadIdx.x;
  const int si = tid * (NQ / THSAMP) + p * (NQ / THSAMP / SPART);
  swx[tid] = sxs[bq + si]; swy[tid] = sys[bq + si]; swz[tid] = szs[bq + si];
  __syncthreads();
  const float qx = sxs[bq + s], qy = sys[bq + s], qz = szs[bq + s];
  unsigned nk[K1];
#pragma unroll
  for (int j = 0; j < K1; ++j) nk[j] = 0xFFFFFFFFu;
  for (int i = 0; i < THSAMP; ++i) {
    float dx = qx - swx[i], dy = qy - swy[i], dz = qz - swz[i];
    float d = dx * dx + dy * dy + dz * dz;
    CHAIN9(__float_as_uint(d));
  }
  thetaOut[(size_t)(bq + s) * SPART + p] = nk[K1 - 1] | 0x1FFFu;
}

// ---- 5. center-out sorted sweep with early stop; P parts (half right, half left) ----
__global__ __launch_bounds__(256) void sweep_kernel(
    const float* __restrict__ sxs, const float* __restrict__ sys,
    const float* __restrict__ szs, const float* __restrict__ shs,
    const unsigned* __restrict__ ssi, const unsigned* __restrict__ binStart,
    const unsigned* __restrict__ thetaIn, unsigned* __restrict__ wsK, int P)
{
  __shared__ unsigned short sbuf[256 * CAP];
  const int b = blockIdx.y, p = blockIdx.z;
  const int s = blockIdx.x * 256 + threadIdx.x;
  const int bq = b * NQ;
  const float qx = sxs[bq + s], qy = sys[bq + s], qz = szs[bq + s];
  const float nqx = -qx, nqy = -qy, nqz = -qz;
  const float qq = qx * qx + qy * qy + qz * qz;
  uint2 th = ((const uint2*)thetaIn)[bq + s];
  const float thetaD1 = __uint_as_float(min(th.x, th.y));
  float thetaS = 0.5f * (thetaD1 - qq) + EPS_S;
  const float r1 = sqrtf(thetaD1) * 1.0001f + 1e-7f;
  unsigned LO = binStart[b * (NB + 1) + binOf(qx - r1)];
  unsigned HI = binStart[b * (NB + 1) + binOf(qx + r1) + 1];
  for (int off = 32; off; off >>= 1) {
    LO = min(LO, (unsigned)__shfl_xor((int)LO, off));
    HI = max(HI, (unsigned)__shfl_xor((int)HI, off));
  }
  const int LOb = __builtin_amdgcn_readfirstlane((int)LO) >> 4;
  const int HIb = (__builtin_amdgcn_readfirstlane((int)HI) - 1) >> 4;
  int mid = (__builtin_amdgcn_readfirstlane(s) + 32) >> 4;
  mid = min(max(mid, LOb), HIb);
  const int PH = P >> 1;
  const bool rightSide = (p < PH);
  int cb = rightSide ? (mid + p) : (mid - 1 - (p - PH));
  const int step = rightSide ? PH : -PH;

  unsigned nk[K1];
#pragma unroll
  for (int j = 0; j < K1; ++j) nk[j] = 0xFFFFFFFFu;
  const unsigned base = (unsigned)threadIdx.x * CAP;
  int cnt = 0;
  int it = 0;
  const float4* __restrict__ x4 = (const float4*)sxs;
  const float4* __restrict__ y4 = (const float4*)sys;
  const float4* __restrict__ z4 = (const float4*)szs;
  const float4* __restrict__ h4 = (const float4*)shs;

  while (cb >= LOb && cb <= HIb) {
    if (__any(cnt >= CAP - 16)) { DRAINS(); }
    const int jb = cb * 16;
    const int ti = (bq + jb) >> 2;
    const float4 X0 = x4[ti], X1 = x4[ti + 1], X2 = x4[ti + 2], X3 = x4[ti + 3];
    const float4 Y0 = y4[ti], Y1 = y4[ti + 1], Y2 = y4[ti + 2], Y3 = y4[ti + 3];
    const float4 Z0 = z4[ti], Z1 = z4[ti + 1], Z2 = z4[ti + 2], Z3 = z4[ti + 3];
    const float4 H0 = h4[ti], H1 = h4[ti + 1], H2 = h4[ti + 2], H3 = h4[ti + 3];
    SCORE4(s0, s1, s2, s3, X0, Y0, Z0, H0);
    SCORE4(s4, s5, s6, s7, X1, Y1, Z1, H1);
    SCORE4(s8, s9, sa, sb, X2, Y2, Z2, H2);
    SCORE4(sc, sd, se, sf, X3, Y3, Z3, H3);
    GPROC(s0, jb + 0);  GPROC(s1, jb + 1);  GPROC(s2, jb + 2);  GPROC(s3, jb + 3);
    GPROC(s4, jb + 4);  GPROC(s5, jb + 5);  GPROC(s6, jb + 6);  GPROC(s7, jb + 7);
    GPROC(s8, jb + 8);  GPROC(s9, jb + 9);  GPROC(sa, jb + 10); GPROC(sb, jb + 11);
    GPROC(sc, jb + 12); GPROC(sd, jb + 13); GPROC(se, jb + 14); GPROC(sf, jb + 15);
    ++it; cb += step;
    if ((it & 3) == 0) {
      DRAINS();
      if (cb < LOb || cb > HIb) break;
      const int je = rightSide ? (cb * 16) : (cb * 16 + 15);
      const float xe = sxs[bq + je];
      const float dxe = rightSide ? (xe - qx) : (qx - xe);
      const float thD = __uint_as_float(nk[K1 - 1] | 0x1FFFu);  // NaN if empty -> no stop
      if (__all((dxe > 0.0f) && (dxe * dxe > thD))) break;
    }
  }
  DRAINS();
#pragma unroll
  for (int j = 0; j < K1; ++j)
    wsK[((size_t)(b * P + p) * K1 + j) * NQ + s] = nk[j];
}

// ---- 6. loss + final fused (R9-proven): merge P*9 keys, drop self, accumulate ----
__global__ __launch_bounds__(64) void loss_kernel(
    const float* __restrict__ pc, const float* __restrict__ pf,
    const float* __restrict__ sxs, const float* __restrict__ sys,
    const float* __restrict__ szs, const unsigned* __restrict__ ssi,
    const unsigned* __restrict__ wsK, float* __restrict__ acc,
    unsigned* __restrict__ doneCtr, float* __restrict__ out,
    int P, int nBlocks)
{
  const int b = blockIdx.y;
  const int s = blockIdx.x * 64 + threadIdx.x;
  const int bq = b * NQ;
  const float* __restrict__ px = pc + (size_t)b * 3 * NQ;
  const float* __restrict__ py = px + NQ;
  const float* __restrict__ pz = px + 2 * NQ;
  const float* __restrict__ fx = pf + (size_t)b * 3 * NQ;
  const float* __restrict__ fy = fx + NQ;
  const float* __restrict__ fz = fx + 2 * NQ;

  const unsigned qorig = ssi[bq + s];
  unsigned nk[KNB];
#pragma unroll
  for (int j = 0; j < KNB; ++j) nk[j] = 0xFFFFFFFFu;

  const int total = P * K1;
  const size_t stride0 = (size_t)b * P * K1;
  for (int m0 = 0; m0 < total; m0 += K1) {
    unsigned kb[K1];
#pragma unroll
    for (int u = 0; u < K1; ++u)
      kb[u] = wsK[(stride0 + m0 + u) * NQ + s];
#pragma unroll
    for (int u = 0; u < K1; ++u) {
      unsigned key = kb[u];
      if ((key & IDXMASK) == qorig) continue;   // drop self
      if (key < nk[KNB - 1]) CHAIN8(key);
    }
  }

  const float qx = sxs[bq + s], qy = sys[bq + s], qz = szs[bq + s];
  const float fqx = fx[qorig], fqy = fy[qorig], fqz = fz[qorig];
  float ssum = 0.f, sdsum = 0.f;
#pragma unroll
  for (int j = 0; j < KNB; ++j) {
    int i = (int)(nk[j] & IDXMASK);
    float dx = qx - px[i], dy = qy - py[i], dz = qz - pz[i];
    float d = dx * dx + dy * dy + dz * dz;
    float e = expf(expf(-2.0f * d));  // exp(exp(-d/alpha)), alpha=0.5
    float gx = fx[i] - fqx, gy = fy[i] - fqy, gz = fz[i] - fqz;
    float diff = sqrtf(gx * gx + gy * gy + gz * gz);
    ssum += e; sdsum += e * diff;
  }

  for (int off = 32; off > 0; off >>= 1) {
    ssum += __shfl_down(ssum, off);
    sdsum += __shfl_down(sdsum, off);
  }
  if (threadIdx.x == 0) {
    atomicAdd(&acc[b * 2 + 0], ssum);
    atomicAdd(&acc[b * 2 + 1], sdsum);
    __threadfence();
    unsigned done = atomicAdd(doneCtr, 1u);
    if (done == (unsigned)(nBlocks - 1)) {
      float sT = 0.f;
      for (int bb = 0; bb < BATCH; ++bb) {
        float se = atomicAdd(&acc[bb * 2 + 0], 0.f);
        float sd = atomicAdd(&acc[bb * 2 + 1], 0.f);
        sT += sd / se;
      }
      out[0] = sT * (1.0f / BATCH);
    }
  }
}

extern "C" void kernel_launch(void* const* d_in, const int* in_sizes, int n_in,
                              void* d_out, int out_size, void* d_ws, size_t ws_size,
                              hipStream_t stream) {
  const float* pc = (const float*)d_in[0];   // pc1:      (4,3,8192) f32
  const float* pf = (const float*)d_in[1];   // pred_flow:(4,3,8192) f32
  float* out = (float*)d_out;

  // workspace layout
  char* w = (char*)d_ws;
  float*    acc      = (float*)w;                         // [0,32)
  unsigned* doneCtr  = (unsigned*)(w + 64);               // [64,68)
  unsigned* hist     = (unsigned*)(w + 256);              // 4*256*4 = 4096 -> [256,4352)
  unsigned* binStart = (unsigned*)(w + 4352);             // 4*257*4 = 4112 -> ends 8464
  const size_t SA = 8704;                                 // 16B-aligned
  float*    sxs = (float*)(w + SA);
  float*    sys = (float*)(w + SA + 1 * 131072);
  float*    szs = (float*)(w + SA + 2 * 131072);
  float*    shs = (float*)(w + SA + 3 * 131072);
  unsigned* ssi = (unsigned*)(w + SA + 4 * 131072);
  const size_t TH = SA + 5 * 131072;                      // 664064, 8B-aligned
  unsigned* thetaBuf = (unsigned*)(w + TH);               // 4*8192*2*4 = 256 KB
  const size_t WK = TH + (size_t)BATCH * NQ * SPART * 4;  // 926208
  unsigned* wsK = (unsigned*)(w + WK);

  const size_t needP8 = WK + (size_t)BATCH * NQ * 8 * K1 * 4;
  const size_t needP4 = WK + (size_t)BATCH * NQ * 4 * K1 * 4;
  const int P = (ws_size >= needP8) ? 8 : ((ws_size >= needP4) ? 4 : 2);

  hipMemsetAsync(d_ws, 0, 4352, stream);  // acc + doneCtr + hist

  hist_kernel<<<dim3(BATCH * NQ / 256), 256, 0, stream>>>(pc, hist);
  prefix_kernel<<<dim3(1), 256, 0, stream>>>(hist, binStart);
  scatter_kernel<<<dim3(BATCH * NQ / 256), 256, 0, stream>>>(
      pc, hist, sxs, sys, szs, shs, ssi);
  theta_kernel<<<dim3(NQ / 256, BATCH, SPART), 256, 0, stream>>>(
      sxs, sys, szs, thetaBuf);
  sweep_kernel<<<dim3(NQ / 256, BATCH, P), 256, 0, stream>>>(
      sxs, sys, szs, shs, ssi, binStart, thetaBuf, wsK, P);
  const int nBlocks = (NQ / 64) * BATCH;
  loss_kernel<<<dim3(NQ / 64, BATCH), 64, 0, stream>>>(
      pc, pf, sxs, sys, szs, ssi, wsK, acc, doneCtr, out, P, nBlocks);
}